// Round 1
// baseline (354.363 us; speedup 1.0000x reference)
//
#include <hip/hip_runtime.h>
#include <hip/hip_bf16.h>

#define NN 8192
#define NFEAT 512
#define NHID 64
#define NCLASS 16
#define NHEAD 4
#define ALPHA 0.1f
#define CSR_STRIDE 1024

__device__ __forceinline__ float lrelu(float x) { return x > 0.f ? x : ALPHA * x; }
__device__ __forceinline__ float elu(float x) { return x > 0.f ? x : __expf(x) - 1.f; }

// ---------------- K1: Wh[h][n][d] = x @ W[h] ----------------
__global__ __launch_bounds__(256) void k_gemm1(const float* __restrict__ x,
                                               const float* __restrict__ W,
                                               float* __restrict__ Wh) {
  __shared__ float As[16][65];
  __shared__ float Bs[16][65];
  const int bm = blockIdx.x * 64;
  const int h  = blockIdx.y;          // 64 cols per block == one head
  const int tid = threadIdx.x;
  const int tx = tid & 15, ty = tid >> 4;
  float acc[4][4] = {};
  for (int k0 = 0; k0 < NFEAT; k0 += 16) {
    {
      int m = tid >> 2;
      int kk = (tid & 3) * 4;
      const float4 xa = *reinterpret_cast<const float4*>(&x[(size_t)(bm + m) * NFEAT + k0 + kk]);
      As[kk + 0][m] = xa.x; As[kk + 1][m] = xa.y; As[kk + 2][m] = xa.z; As[kk + 3][m] = xa.w;
      int c = tid & 63;
      int kb = (tid >> 6) * 4;
#pragma unroll
      for (int u = 0; u < 4; ++u)
        Bs[kb + u][c] = W[((size_t)h * NFEAT + (k0 + kb + u)) * NHID + c];
    }
    __syncthreads();
#pragma unroll
    for (int kk2 = 0; kk2 < 16; ++kk2) {
      float av[4], bv[4];
#pragma unroll
      for (int u = 0; u < 4; ++u) { av[u] = As[kk2][ty * 4 + u]; bv[u] = Bs[kk2][tx * 4 + u]; }
#pragma unroll
      for (int i2 = 0; i2 < 4; ++i2)
#pragma unroll
        for (int j2 = 0; j2 < 4; ++j2) acc[i2][j2] += av[i2] * bv[j2];
    }
    __syncthreads();
  }
#pragma unroll
  for (int i2 = 0; i2 < 4; ++i2)
#pragma unroll
    for (int j2 = 0; j2 < 4; ++j2) {
      int row = bm + ty * 4 + i2;
      int d = tx * 4 + j2;
      Wh[((size_t)h * NN + row) * NHID + d] = acc[i2][j2];
    }
}

// ---------------- K2: f1/f2 rank-1 projections ----------------
__global__ __launch_bounds__(256) void k_f12(const float* __restrict__ Wh,
                                             const float* __restrict__ a,
                                             float* __restrict__ f1,
                                             float* __restrict__ f2) {
  int wid = blockIdx.x * 4 + (threadIdx.x >> 6);
  int lane = threadIdx.x & 63;
  int h = wid >> 13;
  int i = wid & (NN - 1);
  float v = Wh[((size_t)h * NN + i) * NHID + lane];
  float s1 = v * a[h * 2 * NHID + lane];
  float s2 = v * a[h * 2 * NHID + NHID + lane];
#pragma unroll
  for (int off = 32; off; off >>= 1) { s1 += __shfl_xor(s1, off); s2 += __shfl_xor(s2, off); }
  if (lane == 0) { f1[h * NN + i] = s1; f2[h * NN + i] = s2; }
}

// ---------------- K3: layer-1 attention (all 4 heads) + CSR build ----------------
__global__ __launch_bounds__(256) void k_attn1(const float* __restrict__ adj,
                                               const float* __restrict__ Wh,
                                               const float* __restrict__ f1,
                                               const float* __restrict__ f2,
                                               float* __restrict__ hcat,
                                               unsigned short* __restrict__ csr_idx,
                                               int* __restrict__ csr_cnt) {
  __shared__ unsigned short idx[NN];
  __shared__ int cnt;
  const int i = blockIdx.x;
  const int tid = threadIdx.x;
  if (tid == 0) cnt = 0;
  __syncthreads();
  // phase 1: compact the adjacency row
  const float4* arow = reinterpret_cast<const float4*>(adj + (size_t)i * NN);
  for (int b = 0; b < NN / 4; b += 256) {
    float4 v = arow[b + tid];
    int j0 = (b + tid) * 4;
    if (v.x > 0.f) idx[atomicAdd(&cnt, 1)] = (unsigned short)(j0 + 0);
    if (v.y > 0.f) idx[atomicAdd(&cnt, 1)] = (unsigned short)(j0 + 1);
    if (v.z > 0.f) idx[atomicAdd(&cnt, 1)] = (unsigned short)(j0 + 2);
    if (v.w > 0.f) idx[atomicAdd(&cnt, 1)] = (unsigned short)(j0 + 3);
  }
  __syncthreads();
  const int n = cnt;
  // CSR writeout for layer 2
  if (tid == 0) csr_cnt[i] = n;
  for (int k = tid; k < min(n, CSR_STRIDE); k += 256)
    csr_idx[(size_t)i * CSR_STRIDE + k] = idx[k];

  const int wv = tid >> 6;     // wave == head
  const int lane = tid & 63;
  const int h = wv;
  const float* f2h = f2 + (size_t)h * NN;
  // phase 1.5: per-head max of f2 over neighbors (leaky_relu is monotone)
  float mx = -1e30f;
  for (int k = lane; k < n; k += 64) mx = fmaxf(mx, f2h[idx[k]]);
#pragma unroll
  for (int off = 32; off; off >>= 1) mx = fmaxf(mx, __shfl_xor(mx, off));
  const float f1i = f1[(size_t)h * NN + i];
  const float mh = lrelu(f1i + mx);
  // phase 2: weighted gather-accumulate; 4 neighbor streams x 16 dim-quads
  const int sub = lane >> 4;
  const int dq = lane & 15;
  const float4* Wh4 = reinterpret_cast<const float4*>(Wh + (size_t)h * NN * NHID);
  float acc0 = 0.f, acc1 = 0.f, acc2 = 0.f, acc3 = 0.f, sumw = 0.f;
  for (int g = 0; g < n; g += 64) {
    int k = g + lane;
    float wexp = 0.f;
    int jj = 0;
    if (k < n) {
      jj = idx[k];
      wexp = __expf(lrelu(f1i + f2h[jj]) - mh);
    }
    sumw += wexp;
    int lim = min(64, n - g);
    for (int k2 = sub; k2 < lim; k2 += 4) {
      float w = __shfl(wexp, k2);
      int j = __shfl(jj, k2);
      float4 v = Wh4[(size_t)j * 16 + dq];
      acc0 += w * v.x; acc1 += w * v.y; acc2 += w * v.z; acc3 += w * v.w;
    }
  }
#pragma unroll
  for (int off = 16; off <= 32; off <<= 1) {
    acc0 += __shfl_xor(acc0, off);
    acc1 += __shfl_xor(acc1, off);
    acc2 += __shfl_xor(acc2, off);
    acc3 += __shfl_xor(acc3, off);
  }
#pragma unroll
  for (int off = 32; off; off >>= 1) sumw += __shfl_xor(sumw, off);
  if (lane < 16) {
    float inv = 1.f / sumw;
    float4 o;
    o.x = elu(acc0 * inv);
    o.y = elu(acc1 * inv);
    o.z = elu(acc2 * inv);
    o.w = elu(acc3 * inv);
    *reinterpret_cast<float4*>(&hcat[(size_t)i * (NHEAD * NHID) + h * NHID + dq * 4]) = o;
  }
}

// ---------------- K4: Wh2 = hcat @ W_out ; f1o/f2o ----------------
__global__ __launch_bounds__(256) void k_gemm2(const float* __restrict__ hcat,
                                               const float* __restrict__ Wout,
                                               const float* __restrict__ aout,
                                               float* __restrict__ Wh2,
                                               float* __restrict__ f1o,
                                               float* __restrict__ f2o) {
  __shared__ float sW[NHEAD * NHID][NCLASS];   // 256 x 16
  __shared__ float sh[16][NHEAD * NHID];       // 16 x 256
  const int tid = threadIdx.x;
  const int r = tid >> 4, c = tid & 15;
  const int row = blockIdx.x * 16 + r;
  for (int u = tid; u < 256 * 16; u += 256) sW[u >> 4][u & 15] = Wout[u];
  for (int u = tid; u < 16 * 256; u += 256)
    sh[u >> 8][u & 255] = hcat[(size_t)(blockIdx.x * 16 + (u >> 8)) * 256 + (u & 255)];
  __syncthreads();
  float acc = 0.f;
#pragma unroll 8
  for (int f = 0; f < 256; ++f) acc += sh[r][f] * sW[f][c];
  Wh2[(size_t)row * NCLASS + c] = acc;
  float s1 = acc * aout[c];
  float s2 = acc * aout[NCLASS + c];
#pragma unroll
  for (int off = 8; off; off >>= 1) { s1 += __shfl_xor(s1, off); s2 += __shfl_xor(s2, off); }
  if (c == 0) { f1o[row] = s1; f2o[row] = s2; }
}

// ---------------- K5: layer-2 attention + ELU + log_softmax ----------------
__global__ __launch_bounds__(256) void k_attn2(const unsigned short* __restrict__ csr_idx,
                                               const int* __restrict__ csr_cnt,
                                               const float* __restrict__ Wh2,
                                               const float* __restrict__ f1o,
                                               const float* __restrict__ f2o,
                                               float* __restrict__ out) {
  __shared__ unsigned short idx[CSR_STRIDE];
  __shared__ float red[16][17];
  __shared__ float swred[16];
  __shared__ float wmax[4];
  const int i = blockIdx.x;
  const int tid = threadIdx.x;
  int n = min(csr_cnt[i], CSR_STRIDE);
  const unsigned short* ridx = csr_idx + (size_t)i * CSR_STRIDE;
  for (int k = tid; k < n; k += 256) idx[k] = ridx[k];
  __syncthreads();
  float mx = -1e30f;
  for (int k = tid; k < n; k += 256) mx = fmaxf(mx, f2o[idx[k]]);
#pragma unroll
  for (int off = 32; off; off >>= 1) mx = fmaxf(mx, __shfl_xor(mx, off));
  const int wv = tid >> 6, lane = tid & 63;
  if (lane == 0) wmax[wv] = mx;
  __syncthreads();
  mx = fmaxf(fmaxf(wmax[0], wmax[1]), fmaxf(wmax[2], wmax[3]));
  const float f1i = f1o[i];
  const float mh = lrelu(f1i + mx);
  const int c = tid & 15, st = tid >> 4;   // 16 classes x 16 neighbor streams
  float acc = 0.f, sumw = 0.f;
  for (int k = st; k < n; k += 16) {
    int j = idx[k];
    float w = __expf(lrelu(f1i + f2o[j]) - mh);
    if (c == 0) sumw += w;
    acc += w * Wh2[(size_t)j * NCLASS + c];
  }
  red[st][c] = acc;
  if (c == 0) swred[st] = sumw;
  __syncthreads();
  if (tid < 16) {
    float sw = 0.f, av = 0.f;
#pragma unroll
    for (int u = 0; u < 16; ++u) { sw += swred[u]; av += red[u][tid]; }
    float v = elu(av / sw);
    float vm = v;
#pragma unroll
    for (int off = 8; off; off >>= 1) vm = fmaxf(vm, __shfl_xor(vm, off));
    float ex = __expf(v - vm);
#pragma unroll
    for (int off = 8; off; off >>= 1) ex += __shfl_xor(ex, off);
    out[(size_t)i * NCLASS + tid] = v - vm - __logf(ex);
  }
}

extern "C" void kernel_launch(void* const* d_in, const int* in_sizes, int n_in,
                              void* d_out, int out_size, void* d_ws, size_t ws_size,
                              hipStream_t stream) {
  const float* x    = (const float*)d_in[0];
  const float* adj  = (const float*)d_in[1];
  const float* W    = (const float*)d_in[2];
  const float* a    = (const float*)d_in[3];
  const float* Wout = (const float*)d_in[4];
  const float* aout = (const float*)d_in[5];
  float* out = (float*)d_out;
  char* ws = (char*)d_ws;

  float* Wh   = (float*)(ws);                       // 4*8192*64*4 = 8388608 B
  float* f1   = (float*)(ws + 8388608);             // 131072 B
  float* f2   = (float*)(ws + 8519680);             // 131072 B
  float* hcat = (float*)(ws + 8650752);             // 8388608 B
  float* Wh2  = (float*)(ws + 17039360);            // 524288 B
  float* f1o  = (float*)(ws + 17563648);            // 32768 B
  float* f2o  = (float*)(ws + 17596416);            // 32768 B
  int* csr_cnt = (int*)(ws + 17629184);             // 32768 B
  unsigned short* csr_idx = (unsigned short*)(ws + 17661952);  // 16777216 B

  k_gemm1<<<dim3(NN / 64, NHEAD), 256, 0, stream>>>(x, W, Wh);
  k_f12<<<NN * NHEAD / 4, 256, 0, stream>>>(Wh, a, f1, f2);
  k_attn1<<<NN, 256, 0, stream>>>(adj, Wh, f1, f2, hcat, csr_idx, csr_cnt);
  k_gemm2<<<NN / 16, 256, 0, stream>>>(hcat, Wout, aout, Wh2, f1o, f2o);
  k_attn2<<<NN, 256, 0, stream>>>(csr_idx, csr_cnt, Wh2, f1o, f2o, out);
}